// Round 12
// baseline (122.199 us; speedup 1.0000x reference)
//
#include <hip/hip_runtime.h>
#include <hip/hip_fp16.h>
#include <stdint.h>

#define JB 24
#define NP 131072      // 2^17
#define CH 16
#define G  128
#define NPTS (JB*NP)

// workspace sizes in half2 units (1 half2 = 4 B)
#define PLANE_H2 (JB*G*G*CH)   // 6,291,456 half2 per plane array (25.2 MB)
#define LINE_H2  (JB*G*CH)     // 49,152 half2 per line array

typedef _Float16 h2_t __attribute__((ext_vector_type(2)));
typedef unsigned int u32x4 __attribute__((ext_vector_type(4)));

__device__ __forceinline__ float fdot2(uint32_t a, h2_t w, float c) {
#if __has_builtin(__builtin_amdgcn_fdot2)
    return __builtin_amdgcn_fdot2(__builtin_bit_cast(h2_t, a), w, c, false);
#else
    __half2 ha = __builtin_bit_cast(__half2, a);
    float2 fa = __half22float2(ha);
    h2_t wv = w;
    return c + fa.x * (float)wv[0] + fa.y * (float)wv[1];
#endif
}

// ---- pack planes: (J,C,H,W) fp32 -> (plane,J,y,x,c) half2 pairs (v[x], v[x+1]) ----
__global__ __launch_bounds__(256)
void pack_planes_kernel(const float* __restrict__ p0,
                        const float* __restrict__ p1,
                        const float* __restrict__ p2,
                        __half2* __restrict__ wsp) {
    __shared__ float lds[CH * (G + 1)];
    int b = blockIdx.x;
    int y = b & (G - 1);
    int j = (b >> 7) % JB;
    int p = b / (G * JB);
    const float* src = (p == 0 ? p0 : (p == 1 ? p1 : p2))
                       + ((size_t)j * CH) * (G * G) + (size_t)y * G;
    __half2* dst = wsp + ((size_t)(p * JB + j) * G + y) * (G * CH);
    int tid = threadIdx.x;
    for (int idx = tid; idx < G * CH; idx += 256) {
        int c = idx >> 7;
        int x = idx & (G - 1);
        lds[c * (G + 1) + x] = src[(size_t)c * G * G + x];
    }
    __syncthreads();
    for (int idx = tid; idx < G * CH; idx += 256) {
        int x = idx >> 4;
        int c = idx & 15;
        int x1 = (x < G - 1) ? x + 1 : x;
        float a = lds[c * (G + 1) + x];
        float bvv = lds[c * (G + 1) + x1];
        dst[idx] = __floats2half2_rn(a, bvv);
    }
}

// ---- pack lines: (J,C,L) fp32 -> (plane,J,z,c) half2 pairs (l[z], l[z+1]) ----
__global__ __launch_bounds__(256)
void pack_lines_kernel(const float* __restrict__ l0,
                       const float* __restrict__ l1,
                       const float* __restrict__ l2,
                       __half2* __restrict__ wsl) {
    int gid = blockIdx.x * 256 + threadIdx.x;
    if (gid >= 3 * LINE_H2) return;
    int p = gid / LINE_H2;
    int r = gid - p * LINE_H2;
    int j = r >> 11;
    int z = (r >> 4) & (G - 1);
    int c = r & 15;
    int z1 = (z < G - 1) ? z + 1 : z;
    const float* src = (p == 0 ? l0 : (p == 1 ? l1 : l2));
    float a = src[((size_t)j * CH + c) * G + z];
    float bvv = src[((size_t)j * CH + c) * G + z1];
    wsl[gid] = __floats2half2_rn(a, bvv);
}

// ---- main gather: 512 threads/block = 128 pt-slots x 4 pts/slot.
// Lines staged once per block in LDS (24 KB over 512 points = 0.75 lines/pt).
// 512-thread blocks: 8-wave workgroup quantum -> up to 4 blocks/CU (vs 1024's ~1).
__global__ __launch_bounds__(512)
void tensorf_lds512_kernel(const float* __restrict__ xyz,
                           const uint32_t* __restrict__ wp,   // half2 units
                           const uint32_t* __restrict__ wl,   // half2 units
                           float* __restrict__ out) {
    const int NWG = NPTS / 512;         // 6144 blocks, 512 points each
    int bid = blockIdx.x;
    int wg = (bid & 7) * (NWG >> 3) + (bid >> 3);   // XCD-contiguous chunks
    int tid = threadIdx.x;
    int ptblk = wg << 9;                // first point of this block
    int j = ptblk >> 17;                // whole block same j (256 blocks per j)

    // ---- stage the 3 line tables for this j: 3 * 2048 uint32 = 24 KB ----
    __shared__ uint32_t slines[3 * 2048];
    {
        u32x4* dst4 = (u32x4*)slines;
        for (int idx = tid; idx < 1536; idx += 512) {
            int i = idx >> 9;           // 512 u32x4 per table
            int r = idx & 511;
            dst4[idx] = ((const u32x4*)(wl + (((size_t)i * JB + j) << 11)))[r];
        }
    }
    __syncthreads();

    int l4 = tid & 3;                   // channel quad 0..3
    int slot = tid >> 2;                // 0..127

    const int M0[3] = {0, 0, 1};
    const int M1[3] = {1, 2, 2};
    const int VZ[3] = {2, 1, 0};

    #pragma unroll
    for (int p = 0; p < 4; ++p) {
        int pt = ptblk + (p << 7) + slot;

        float cx = xyz[(size_t)pt * 3 + 0];
        float cy = xyz[(size_t)pt * 3 + 1];
        float cz = xyz[(size_t)pt * 3 + 2];
        const float co[3] = {cx, cy, cz};

        float4 acc = {0.f, 0.f, 0.f, 0.f};
        #pragma unroll
        for (int i = 0; i < 3; ++i) {
            // inputs are strictly in [-1, 1) -> indices in [0,126], no clamps needed
            float fx = (co[M0[i]] + 1.f) * 63.5f;
            float fy = (co[M1[i]] + 1.f) * 63.5f;
            float fz = (co[VZ[i]] + 1.f) * 63.5f;
            float f0x = floorf(fx);
            float f0y = floorf(fy);
            float f0z = floorf(fz);
            int x0 = (int)f0x, y0 = (int)f0y, z0 = (int)f0z;
            float wx = fx - f0x, wy = fy - f0y, wz = fz - f0z;

            h2_t wxh = {(_Float16)(1.f - wx), (_Float16)wx};
            h2_t wzh = {(_Float16)(1.f - wz), (_Float16)wz};

            // plane entry base (half2 units): (i*24+j)*2^18 + (y0*128+x0)*16 + l4*4
            int pb = ((i * JB + j) << 18) + (((y0 << 7) + x0) << 4) + (l4 << 2);
            u32x4 A = *(const u32x4*)(wp + pb);              // row y0
            u32x4 B = *(const u32x4*)(wp + pb + (G << 4));   // row y0+1
            u32x4 C = *(const u32x4*)(slines + (i << 11) + (z0 << 4) + (l4 << 2));

            float t0 = fdot2(A.x, wxh, 0.f);
            float t1 = fdot2(A.y, wxh, 0.f);
            float t2 = fdot2(A.z, wxh, 0.f);
            float t3 = fdot2(A.w, wxh, 0.f);
            float b0 = fdot2(B.x, wxh, 0.f);
            float b1 = fdot2(B.y, wxh, 0.f);
            float b2 = fdot2(B.z, wxh, 0.f);
            float b3 = fdot2(B.w, wxh, 0.f);
            float v0 = fdot2(C.x, wzh, 0.f);
            float v1 = fdot2(C.y, wzh, 0.f);
            float v2 = fdot2(C.z, wzh, 0.f);
            float v3 = fdot2(C.w, wzh, 0.f);
            float q0 = t0 + (b0 - t0) * wy;
            float q1 = t1 + (b1 - t1) * wy;
            float q2 = t2 + (b2 - t2) * wy;
            float q3 = t3 + (b3 - t3) * wy;
            acc.x = fmaf(q0, v0, acc.x);
            acc.y = fmaf(q1, v1, acc.y);
            acc.z = fmaf(q2, v2, acc.z);
            acc.w = fmaf(q3, v3, acc.w);
        }
        float s = (acc.x + acc.y) + (acc.z + acc.w);
        s += __shfl_xor(s, 1);
        s += __shfl_xor(s, 2);
        if (l4 == 0) out[pt] = fmaxf(s, 0.f);
    }
}

// ---------------- fallback: direct layout fp32 (if ws too small) ----------------
__global__ __launch_bounds__(256)
void tensorf_direct_kernel(const float* __restrict__ xyz,
                           const float* __restrict__ p0,
                           const float* __restrict__ p1,
                           const float* __restrict__ p2,
                           const float* __restrict__ l0,
                           const float* __restrict__ l1,
                           const float* __restrict__ l2,
                           float* __restrict__ out) {
    int gid = blockIdx.x * 256 + threadIdx.x;
    if (gid >= NPTS) return;
    int j = gid >> 17;
    float cx = xyz[(size_t)gid * 3 + 0];
    float cy = xyz[(size_t)gid * 3 + 1];
    float cz = xyz[(size_t)gid * 3 + 2];
    const float co[3] = {cx, cy, cz};
    const int M0[3] = {0, 0, 1};
    const int M1[3] = {1, 2, 2};
    const int VZ[3] = {2, 1, 0};
    const float* PP[3] = {p0, p1, p2};
    const float* LL[3] = {l0, l1, l2};

    float acc = 0.f;
    #pragma unroll
    for (int i = 0; i < 3; ++i) {
        float fx = (co[M0[i]] + 1.f) * 63.5f;
        float fy = (co[M1[i]] + 1.f) * 63.5f;
        float fz = (co[VZ[i]] + 1.f) * 63.5f;
        float f0x = fminf(fmaxf(floorf(fx), 0.f), 127.f);
        float f0y = fminf(fmaxf(floorf(fy), 0.f), 127.f);
        float f0z = fminf(fmaxf(floorf(fz), 0.f), 127.f);
        int x0 = (int)f0x, y0 = (int)f0y, z0 = (int)f0z;
        int x1 = min(x0 + 1, G - 1);
        int y1 = min(y0 + 1, G - 1);
        int z1 = min(z0 + 1, G - 1);
        float wx = fx - f0x, wy = fy - f0y, wz = fz - f0z;

        const float* p = PP[i] + (size_t)j * CH * G * G;
        const float* l = LL[i] + (size_t)j * CH * G;
        for (int c = 0; c < CH; ++c) {
            const float* pc = p + (size_t)c * G * G;
            float v00 = pc[(size_t)y0 * G + x0];
            float v01 = pc[(size_t)y0 * G + x1];
            float v10 = pc[(size_t)y1 * G + x0];
            float v11 = pc[(size_t)y1 * G + x1];
            float lc0 = l[(size_t)c * G + z0];
            float lc1 = l[(size_t)c * G + z1];
            float top = v00 + (v01 - v00) * wx;
            float bot = v10 + (v11 - v10) * wx;
            float pv  = top + (bot - top) * wy;
            float lv  = lc0 + (lc1 - lc0) * wz;
            acc += pv * lv;
        }
    }
    out[gid] = fmaxf(acc, 0.f);
}

extern "C" void kernel_launch(void* const* d_in, const int* in_sizes, int n_in,
                              void* d_out, int out_size, void* d_ws, size_t ws_size,
                              hipStream_t stream) {
    const float* xyz = (const float*)d_in[0];
    const float* p0  = (const float*)d_in[1];
    const float* l0  = (const float*)d_in[2];
    const float* p1  = (const float*)d_in[3];
    const float* l1  = (const float*)d_in[4];
    const float* p2  = (const float*)d_in[5];
    const float* l2  = (const float*)d_in[6];
    float* out = (float*)d_out;

    const size_t need = ((size_t)3 * PLANE_H2 + (size_t)3 * LINE_H2) * sizeof(__half2);

    if (ws_size >= need) {
        __half2* wsp = (__half2*)d_ws;
        __half2* wsl = wsp + (size_t)3 * PLANE_H2;
        pack_planes_kernel<<<3 * JB * G, 256, 0, stream>>>(p0, p1, p2, wsp);
        pack_lines_kernel<<<(3 * LINE_H2 + 255) / 256, 256, 0, stream>>>(l0, l1, l2, wsl);
        tensorf_lds512_kernel<<<NPTS / 512, 512, 0, stream>>>(
            xyz, (const uint32_t*)wsp, (const uint32_t*)wsl, out);
    } else {
        tensorf_direct_kernel<<<(NPTS + 255) / 256, 256, 0, stream>>>(xyz, p0, p1, p2, l0, l1, l2, out);
    }
}

// Round 13
// 120.454 us; speedup vs baseline: 1.0145x; 1.0145x over previous
//
#include <hip/hip_runtime.h>
#include <hip/hip_fp16.h>
#include <stdint.h>

#define JB 24
#define NP 131072      // 2^17
#define CH 16
#define G  128
#define NPTS (JB*NP)

// workspace sizes in half2 units (1 half2 = 4 B)
#define PLANE_H2 (JB*G*G*CH)   // 6,291,456 half2 per plane array (25.2 MB)
#define LINE_H2  (JB*G*CH)     // 49,152 half2 per line array

typedef _Float16 h2_t __attribute__((ext_vector_type(2)));
typedef unsigned int u32x4 __attribute__((ext_vector_type(4)));

__device__ __forceinline__ float fdot2(uint32_t a, h2_t w, float c) {
#if __has_builtin(__builtin_amdgcn_fdot2)
    return __builtin_amdgcn_fdot2(__builtin_bit_cast(h2_t, a), w, c, false);
#else
    __half2 ha = __builtin_bit_cast(__half2, a);
    float2 fa = __half22float2(ha);
    h2_t wv = w;
    return c + fa.x * (float)wv[0] + fa.y * (float)wv[1];
#endif
}

// ---- pack planes: (J,C,H,W) fp32 -> (plane,J,y,x,c) half2 pairs (v[x], v[x+1]) ----
__global__ __launch_bounds__(256)
void pack_planes_kernel(const float* __restrict__ p0,
                        const float* __restrict__ p1,
                        const float* __restrict__ p2,
                        __half2* __restrict__ wsp) {
    __shared__ float lds[CH * (G + 1)];
    int b = blockIdx.x;
    int y = b & (G - 1);
    int j = (b >> 7) % JB;
    int p = b / (G * JB);
    const float* src = (p == 0 ? p0 : (p == 1 ? p1 : p2))
                       + ((size_t)j * CH) * (G * G) + (size_t)y * G;
    __half2* dst = wsp + ((size_t)(p * JB + j) * G + y) * (G * CH);
    int tid = threadIdx.x;
    for (int idx = tid; idx < G * CH; idx += 256) {
        int c = idx >> 7;
        int x = idx & (G - 1);
        lds[c * (G + 1) + x] = src[(size_t)c * G * G + x];
    }
    __syncthreads();
    for (int idx = tid; idx < G * CH; idx += 256) {
        int x = idx >> 4;
        int c = idx & 15;
        int x1 = (x < G - 1) ? x + 1 : x;
        float a = lds[c * (G + 1) + x];
        float bvv = lds[c * (G + 1) + x1];
        dst[idx] = __floats2half2_rn(a, bvv);
    }
}

// ---- pack lines: (J,C,L) fp32 -> (plane,J,z,c) half2 pairs (l[z], l[z+1]) ----
__global__ __launch_bounds__(256)
void pack_lines_kernel(const float* __restrict__ l0,
                       const float* __restrict__ l1,
                       const float* __restrict__ l2,
                       __half2* __restrict__ wsl) {
    int gid = blockIdx.x * 256 + threadIdx.x;
    if (gid >= 3 * LINE_H2) return;
    int p = gid / LINE_H2;
    int r = gid - p * LINE_H2;
    int j = r >> 11;
    int z = (r >> 4) & (G - 1);
    int c = r & 15;
    int z1 = (z < G - 1) ? z + 1 : z;
    const float* src = (p == 0 ? l0 : (p == 1 ? l1 : l2));
    float a = src[((size_t)j * CH + c) * G + z];
    float bvv = src[((size_t)j * CH + c) * G + z1];
    wsl[gid] = __floats2half2_rn(a, bvv);
}

// ---- main gather: 1024 threads/block = 256 pt-slots x 4 pts/slot.
// Lines staged once per block in LDS; coords/floors/weights hoisted (shared
// across the 3 projections: axes are permutations of (x,y,z)).
__global__ __launch_bounds__(1024)
void tensorf_lds1k_kernel(const float* __restrict__ xyz,
                          const uint32_t* __restrict__ wp,   // half2 units
                          const uint32_t* __restrict__ wl,   // half2 units
                          float* __restrict__ out) {
    const int NWG = NPTS / 1024;        // 3072 blocks, 1024 points each
    int bid = blockIdx.x;
    int wg = (bid & 7) * (NWG >> 3) + (bid >> 3);   // XCD-contiguous chunks
    int tid = threadIdx.x;
    int ptblk = wg << 10;               // first point of this block
    int j = ptblk >> 17;                // whole block same j (128 blocks per j)

    // ---- stage the 3 line tables for this j: 3 * 2048 uint32 = 24 KB ----
    __shared__ uint32_t slines[3 * 2048];
    {
        u32x4* dst4 = (u32x4*)slines;
        for (int idx = tid; idx < 1536; idx += 1024) {
            int i = idx >> 9;           // 512 u32x4 per table
            int r = idx & 511;
            dst4[idx] = ((const u32x4*)(wl + (((size_t)i * JB + j) << 11)))[r];
        }
    }
    __syncthreads();

    int l4 = tid & 3;                   // channel quad 0..3
    int slot = tid >> 2;                // 0..255

    // projection i: plane axes (M0,M1), line axis VZ
    // M0 = {0,0,1}, M1 = {1,2,2}, VZ = {2,1,0}
    #pragma unroll
    for (int p = 0; p < 4; ++p) {
        int pt = ptblk + (p << 8) + slot;

        float cx = xyz[(size_t)pt * 3 + 0];
        float cy = xyz[(size_t)pt * 3 + 1];
        float cz = xyz[(size_t)pt * 3 + 2];

        // shared per-point scaled coords (inputs strictly in [-1,1))
        float fa = (cx + 1.f) * 63.5f;
        float fb = (cy + 1.f) * 63.5f;
        float fc = (cz + 1.f) * 63.5f;
        float f0a = floorf(fa), f0b = floorf(fb), f0c = floorf(fc);
        int ia = (int)f0a, ib = (int)f0b, ic = (int)f0c;
        float wa = fa - f0a, wb = fb - f0b, wc = fc - f0c;
        h2_t wah = {(_Float16)(1.f - wa), (_Float16)wa};
        h2_t wbh = {(_Float16)(1.f - wb), (_Float16)wb};
        h2_t wch = {(_Float16)(1.f - wc), (_Float16)wc};

        // per-projection (x0,y0,z0) index triples and weight selections
        const int   X0[3] = {ia, ia, ib};
        const int   Y0[3] = {ib, ic, ic};
        const int   Z0[3] = {ic, ib, ia};
        const h2_t  WX[3] = {wah, wah, wbh};
        const float WY[3] = {wb, wc, wc};
        const h2_t  WZ[3] = {wch, wbh, wah};

        float4 acc = {0.f, 0.f, 0.f, 0.f};
        #pragma unroll
        for (int i = 0; i < 3; ++i) {
            int pb = ((i * JB + j) << 18) + (((Y0[i] << 7) + X0[i]) << 4) + (l4 << 2);
            u32x4 A = *(const u32x4*)(wp + pb);              // row y0
            u32x4 B = *(const u32x4*)(wp + pb + (G << 4));   // row y0+1
            u32x4 C = *(const u32x4*)(slines + (i << 11) + (Z0[i] << 4) + (l4 << 2));
            h2_t wxh = WX[i], wzh = WZ[i];
            float wy = WY[i];

            float t0 = fdot2(A.x, wxh, 0.f);
            float t1 = fdot2(A.y, wxh, 0.f);
            float t2 = fdot2(A.z, wxh, 0.f);
            float t3 = fdot2(A.w, wxh, 0.f);
            float b0 = fdot2(B.x, wxh, 0.f);
            float b1 = fdot2(B.y, wxh, 0.f);
            float b2 = fdot2(B.z, wxh, 0.f);
            float b3 = fdot2(B.w, wxh, 0.f);
            float v0 = fdot2(C.x, wzh, 0.f);
            float v1 = fdot2(C.y, wzh, 0.f);
            float v2 = fdot2(C.z, wzh, 0.f);
            float v3 = fdot2(C.w, wzh, 0.f);
            float q0 = t0 + (b0 - t0) * wy;
            float q1 = t1 + (b1 - t1) * wy;
            float q2 = t2 + (b2 - t2) * wy;
            float q3 = t3 + (b3 - t3) * wy;
            acc.x = fmaf(q0, v0, acc.x);
            acc.y = fmaf(q1, v1, acc.y);
            acc.z = fmaf(q2, v2, acc.z);
            acc.w = fmaf(q3, v3, acc.w);
        }
        float s = (acc.x + acc.y) + (acc.z + acc.w);
        s += __shfl_xor(s, 1);
        s += __shfl_xor(s, 2);
        if (l4 == 0) out[pt] = fmaxf(s, 0.f);
    }
}

// ---------------- fallback: direct layout fp32 (if ws too small) ----------------
__global__ __launch_bounds__(256)
void tensorf_direct_kernel(const float* __restrict__ xyz,
                           const float* __restrict__ p0,
                           const float* __restrict__ p1,
                           const float* __restrict__ p2,
                           const float* __restrict__ l0,
                           const float* __restrict__ l1,
                           const float* __restrict__ l2,
                           float* __restrict__ out) {
    int gid = blockIdx.x * 256 + threadIdx.x;
    if (gid >= NPTS) return;
    int j = gid >> 17;
    float cx = xyz[(size_t)gid * 3 + 0];
    float cy = xyz[(size_t)gid * 3 + 1];
    float cz = xyz[(size_t)gid * 3 + 2];
    const float co[3] = {cx, cy, cz};
    const int M0[3] = {0, 0, 1};
    const int M1[3] = {1, 2, 2};
    const int VZ[3] = {2, 1, 0};
    const float* PP[3] = {p0, p1, p2};
    const float* LL[3] = {l0, l1, l2};

    float acc = 0.f;
    #pragma unroll
    for (int i = 0; i < 3; ++i) {
        float fx = (co[M0[i]] + 1.f) * 63.5f;
        float fy = (co[M1[i]] + 1.f) * 63.5f;
        float fz = (co[VZ[i]] + 1.f) * 63.5f;
        float f0x = fminf(fmaxf(floorf(fx), 0.f), 127.f);
        float f0y = fminf(fmaxf(floorf(fy), 0.f), 127.f);
        float f0z = fminf(fmaxf(floorf(fz), 0.f), 127.f);
        int x0 = (int)f0x, y0 = (int)f0y, z0 = (int)f0z;
        int x1 = min(x0 + 1, G - 1);
        int y1 = min(y0 + 1, G - 1);
        int z1 = min(z0 + 1, G - 1);
        float wx = fx - f0x, wy = fy - f0y, wz = fz - f0z;

        const float* p = PP[i] + (size_t)j * CH * G * G;
        const float* l = LL[i] + (size_t)j * CH * G;
        for (int c = 0; c < CH; ++c) {
            const float* pc = p + (size_t)c * G * G;
            float v00 = pc[(size_t)y0 * G + x0];
            float v01 = pc[(size_t)y0 * G + x1];
            float v10 = pc[(size_t)y1 * G + x0];
            float v11 = pc[(size_t)y1 * G + x1];
            float lc0 = l[(size_t)c * G + z0];
            float lc1 = l[(size_t)c * G + z1];
            float top = v00 + (v01 - v00) * wx;
            float bot = v10 + (v11 - v10) * wx;
            float pv  = top + (bot - top) * wy;
            float lv  = lc0 + (lc1 - lc0) * wz;
            acc += pv * lv;
        }
    }
    out[gid] = fmaxf(acc, 0.f);
}

extern "C" void kernel_launch(void* const* d_in, const int* in_sizes, int n_in,
                              void* d_out, int out_size, void* d_ws, size_t ws_size,
                              hipStream_t stream) {
    const float* xyz = (const float*)d_in[0];
    const float* p0  = (const float*)d_in[1];
    const float* l0  = (const float*)d_in[2];
    const float* p1  = (const float*)d_in[3];
    const float* l1  = (const float*)d_in[4];
    const float* p2  = (const float*)d_in[5];
    const float* l2  = (const float*)d_in[6];
    float* out = (float*)d_out;

    const size_t need = ((size_t)3 * PLANE_H2 + (size_t)3 * LINE_H2) * sizeof(__half2);

    if (ws_size >= need) {
        __half2* wsp = (__half2*)d_ws;
        __half2* wsl = wsp + (size_t)3 * PLANE_H2;
        pack_planes_kernel<<<3 * JB * G, 256, 0, stream>>>(p0, p1, p2, wsp);
        pack_lines_kernel<<<(3 * LINE_H2 + 255) / 256, 256, 0, stream>>>(l0, l1, l2, wsl);
        tensorf_lds1k_kernel<<<NPTS / 1024, 1024, 0, stream>>>(
            xyz, (const uint32_t*)wsp, (const uint32_t*)wsl, out);
    } else {
        tensorf_direct_kernel<<<(NPTS + 255) / 256, 256, 0, stream>>>(xyz, p0, p1, p2, l0, l1, l2, out);
    }
}